// Round 1
// baseline (96.060 us; speedup 1.0000x reference)
//
#include <hip/hip_runtime.h>
#include <math.h>

#define C_IN 32
#define O_OUT 32
#define HIMG 112
#define WIMG 112
#define TS 8     // spatial tile 8x8
#define OG 8     // output channels per thread (4 wave-groups x 8 = 32)

// Tropical (max-min) 3x3 conv, 'same' padding with -inf.
// out[n,o,i,j] = max_{c,kh,kw} min(x[n,c,i+kh-1,j+kw-1], w[o,c,kh,kw])
__global__ __launch_bounds__(256, 6) void semiconv_kernel(
    const float* __restrict__ x, const float* __restrict__ kern,
    float* __restrict__ out)
{
    __shared__ float lds[C_IN * 10 * 10];   // [c][r][col], 10x10 haloed tile

    const int tid = threadIdx.x;
    const int tj0 = blockIdx.x * TS;
    const int ti0 = blockIdx.y * TS;
    const int n   = blockIdx.z;

    const float* xn = x + (size_t)n * (C_IN * HIMG * WIMG);

    // Stage x[n, :, ti0-1 .. ti0+8, tj0-1 .. tj0+8] with -inf out-of-bounds.
    #pragma unroll 1
    for (int idx = tid; idx < C_IN * 100; idx += 256) {
        int c   = idx / 100;
        int rem = idx - c * 100;
        int r   = rem / 10;
        int col = rem - r * 10;
        int gi = ti0 - 1 + r;
        int gj = tj0 - 1 + col;
        float v = -INFINITY;
        if ((unsigned)gi < (unsigned)HIMG && (unsigned)gj < (unsigned)WIMG)
            v = xn[c * (HIMG * WIMG) + gi * WIMG + gj];
        lds[idx] = v;
    }
    __syncthreads();

    const int sp = tid & 63;          // spatial position within wave (8x8)
    const int tx = sp & 7;
    const int ty = sp >> 3;
    // wave-uniform o-group base; readfirstlane makes uniformity provable
    // so weight loads become s_load (SGPR operand into v_min_f32).
    const int o0 = __builtin_amdgcn_readfirstlane((tid >> 6) * OG);

    float acc[OG];
    #pragma unroll
    for (int i = 0; i < OG; ++i) acc[i] = -INFINITY;

    #pragma unroll 1
    for (int c = 0; c < C_IN; ++c) {
        const float* xs = &lds[c * 100 + ty * 10 + tx];
        float xv[9];
        #pragma unroll
        for (int kh = 0; kh < 3; ++kh)
            #pragma unroll
            for (int kw = 0; kw < 3; ++kw)
                xv[kh * 3 + kw] = xs[kh * 10 + kw];

        const float* wb = kern + ((size_t)o0 * C_IN + c) * 9;
        #pragma unroll
        for (int oo = 0; oo < OG; ++oo) {
            const float* wp = wb + (size_t)oo * (C_IN * 9);
            float m0 = fminf(xv[0], wp[0]);
            float m1 = fminf(xv[1], wp[1]);
            float m2 = fminf(xv[2], wp[2]);
            float m3 = fminf(xv[3], wp[3]);
            float m4 = fminf(xv[4], wp[4]);
            float m5 = fminf(xv[5], wp[5]);
            float m6 = fminf(xv[6], wp[6]);
            float m7 = fminf(xv[7], wp[7]);
            float m8 = fminf(xv[8], wp[8]);
            // fmaxf(fmaxf(a,b),c) -> v_max3_f32
            float r0 = fmaxf(fmaxf(m0, m1), m2);
            float r1 = fmaxf(fmaxf(m3, m4), m5);
            float r2 = fmaxf(fmaxf(m6, m7), m8);
            acc[oo] = fmaxf(acc[oo], fmaxf(fmaxf(r0, r1), r2));
        }
    }

    float* op = out + (((size_t)n * O_OUT + o0) * HIMG + (ti0 + ty)) * WIMG
                    + (tj0 + tx);
    #pragma unroll
    for (int oo = 0; oo < OG; ++oo)
        op[(size_t)oo * (HIMG * WIMG)] = acc[oo];
}

extern "C" void kernel_launch(void* const* d_in, const int* in_sizes, int n_in,
                              void* d_out, int out_size, void* d_ws, size_t ws_size,
                              hipStream_t stream) {
    const float* x    = (const float*)d_in[0];
    const float* kern = (const float*)d_in[1];
    float* out        = (float*)d_out;
    dim3 grid(WIMG / TS, HIMG / TS, 8);   // (14, 14, 8)
    dim3 block(256);
    semiconv_kernel<<<grid, block, 0, stream>>>(x, kern, out);
}